// Round 17
// baseline (965.849 us; speedup 1.0000x reference)
//
#include <hip/hip_runtime.h>
#include <stdint.h>

typedef short short8 __attribute__((ext_vector_type(8)));
typedef float f32x4 __attribute__((ext_vector_type(4)));
typedef int int8v __attribute__((ext_vector_type(8)));

#define B_   16
#define C_   512
#define HW_  1024
#define PADP 1156   // 34*34
#define INV256 0.00390625f

__device__ __forceinline__ unsigned short f2bf(float f) {
  union { float f; unsigned u; } v; v.f = f;
  unsigned r = v.u + 0x7FFFu + ((v.u >> 16) & 1u);
  return (unsigned short)(r >> 16);
}
__device__ __forceinline__ float bf2f(unsigned short h) {
  union { unsigned u; float f; } v; v.u = ((unsigned)h) << 16;
  return v.f;
}
// f32 -> OCP e4m3 via HW converter (gfx950 native fp8 = OCP)
__device__ __forceinline__ unsigned char f2e4m3(float f) {
  return (unsigned char)(__builtin_amdgcn_cvt_pk_fp8_f32(f, f, 0, false) & 0xFF);
}
// 4x f32 -> packed 4x e4m3 in one u32
__device__ __forceinline__ unsigned pk4_e4m3(float a, float b, float c, float d) {
  int lo = __builtin_amdgcn_cvt_pk_fp8_f32(a, b, 0, false);
  return (unsigned)__builtin_amdgcn_cvt_pk_fp8_f32(c, d, lo, true);
}
// f32 -> fp4 e2m1 nibble, RNE onto {0,.5,1,1.5,2,3,4,6}, saturating
__device__ __forceinline__ unsigned f2e2m1(float f) {
  union { float f; unsigned u; } v; v.f = f;
  unsigned s = (v.u >> 28) & 8u;
  v.u &= 0x7FFFFFFFu;
  float a = v.f;
  unsigned m;
  if (a <= 0.25f) m = 0;
  else if (a < 0.75f) m = 1;
  else if (a <= 1.25f) m = 2;
  else if (a < 1.75f) m = 3;
  else if (a <= 2.5f) m = 4;
  else if (a < 3.5f) m = 5;
  else if (a <= 5.0f) m = 6;
  else m = 7;
  return s | m;
}

#define GLL16(g, l)                                                            \
  __builtin_amdgcn_global_load_lds(                                            \
      (const __attribute__((address_space(1))) void*)(g),                      \
      (__attribute__((address_space(3))) void*)(l), 16, 0, 0)

#define MFMA16(a, b, c) __builtin_amdgcn_mfma_f32_16x16x32_bf16((a), (b), (c), 0, 0, 0)
#define MFMA8S(a, b, c)                                                        \
  __builtin_amdgcn_mfma_scale_f32_16x16x128_f8f6f4(                            \
      (a), (b), (c), 0, 0, 0, 0x7F7F7F7F, 0, 0x7F7F7F7F)
#define MFMA4S(a, b, c)                                                        \
  __builtin_amdgcn_mfma_scale_f32_16x16x128_f8f6f4(                            \
      (a), (b), (c), 4, 4, 0, 0x7F7F7F7F, 0, 0x7F7F7F7F)

// ------ pack x: NCHW f32 -> padded NHWC fp4 nibbles (256 B/pos row) ---------
__global__ void pack_x_kernel(const float* __restrict__ x,
                              unsigned char* __restrict__ xp4) {
  __shared__ float lds[64][69];
  int b  = blockIdx.z;
  int c0 = blockIdx.y * 64;
  int p0 = blockIdx.x * 64;
  int tid = threadIdx.x;
  int pi = tid & 63, cq = tid >> 6;
#pragma unroll
  for (int i = 0; i < 16; ++i) {
    int cl = cq * 16 + i;
    lds[cl][pi] = x[((size_t)(b * C_ + c0 + cl)) * HW_ + p0 + pi];
  }
  __syncthreads();
  int pl = tid >> 2, u = tid & 3;
  int p  = p0 + pl;
  int pp = ((p >> 5) + 1) * 34 + (p & 31) + 1;
  union { unsigned char c[8]; uint2 v; } ob;
#pragma unroll
  for (int j = 0; j < 8; ++j) {
    int cl = u * 16 + 2 * j;
    ob.c[j] = (unsigned char)(f2e2m1(lds[cl][pl]) |
                              (f2e2m1(lds[cl + 1][pl]) << 4));
  }
  *(uint2*)&xp4[((size_t)(b * PADP + pp)) * 256 + (c0 >> 1) + u * 8] = ob.v;
}

// -- pack w_qkv: [oc][ic][t] f32 -> fp4 W2T[oc][k=t*512+ic] x256, 2304 B/row -
__global__ void pack_wqkv_kernel(const float* __restrict__ w,
                                 unsigned char* __restrict__ w2t4) {
  __shared__ float tmp[4608];
  int oc = blockIdx.x;
  for (int s = threadIdx.x; s < 4608; s += 256)
    tmp[s] = w[(size_t)oc * 4608 + s] * 256.f;
  __syncthreads();
  for (int d4 = threadIdx.x; d4 < 576; d4 += 256) {
    uchar4 ob;
#pragma unroll
    for (int i = 0; i < 4; ++i) {
      int k0 = (d4 * 4 + i) * 2;           // even k; pair within same tap
      int t = k0 >> 9, ic = k0 & 511;
      unsigned lo = f2e2m1(tmp[ic * 9 + t]);
      unsigned hi = f2e2m1(tmp[(ic + 1) * 9 + t]);
      ((unsigned char*)&ob)[i] = (unsigned char)(lo | (hi << 4));
    }
    *(uchar4*)&w2t4[(size_t)oc * 2304 + d4 * 4] = ob;
  }
}

// ---------------- pack w_proj: f32 -> bf16 ----------------------------------
__global__ void pack_wproj_kernel(const float* __restrict__ w,
                                  unsigned short* __restrict__ wp) {
  int i = blockIdx.x * 256 + threadIdx.x;
  wp[i] = f2bf(w[i]);
}

// ------- conv3x3 implicit GEMM, MX-fp4, BK=256 els (128 B rows), 2-phase ----
// st loop fully unrolled: tap/half/off become compile-time constants so every
// staging/read address folds to base+imm (VALU was the busiest pipe at 43%).
__launch_bounds__(256, 4)
__global__ void conv_qkv_kernel(const unsigned char* __restrict__ xp4,
                                const unsigned char* __restrict__ w2t4,
                                const float* __restrict__ bqkv,
                                unsigned char* __restrict__ qk8,
                                unsigned char* __restrict__ vT8) {
  __shared__ __attribute__((aligned(16))) unsigned char As[128 * 128];
  __shared__ __attribute__((aligned(16))) unsigned char Bs[128 * 128];
  int b  = blockIdx.z;
  int m0 = blockIdx.y * 128;
  int n0 = blockIdx.x * 128;
  int tid = threadIdx.x;
  int w = tid >> 6, lane = tid & 63;
  int wm = w >> 1, wn = w & 1;
  int l15 = lane & 15, l4 = lane >> 4;
  f32x4 acc[4][4];
#pragma unroll
  for (int i = 0; i < 4; ++i)
#pragma unroll
    for (int j = 0; j < 4; ++j) acc[i][j] = (f32x4){0.f, 0.f, 0.f, 0.f};

  int sr = tid >> 3;  // staging row within 32-row group (8 x 16B = 128 B row)
  int sc = tid & 7;

#pragma unroll
  for (int st = 0; st < 18; ++st) {
    int tap  = st >> 1;
    int half = st & 1;  // which 256-element half of the tap's 512 channels
    int off  = (tap / 3 - 1) * 34 + (tap % 3) - 1;
#pragma unroll
    for (int is = 0; is < 4; ++is) {
      int r  = is * 32 + sr;
      int p  = m0 + r;
      int pp = ((p >> 5) + 1) * 34 + (p & 31) + 1 + off;
      int cg = sc ^ (r & 7);
      GLL16(xp4 + ((size_t)(b * PADP + pp)) * 256 + half * 128 + cg * 16,
            &As[is * 4096 + tid * 16]);
    }
#pragma unroll
    for (int is = 0; is < 4; ++is) {
      int r  = is * 32 + sr;
      int cg = sc ^ (r & 7);
      GLL16(w2t4 + (size_t)(n0 + r) * 2304 + st * 128 + cg * 16,
            &Bs[is * 4096 + tid * 16]);
    }
    __syncthreads();
#pragma unroll
    for (int h = 0; h < 2; ++h) {
      int8v a8[4], b8[4];
#pragma unroll
      for (int mi = 0; mi < 4; ++mi) {
        int r = wm * 64 + mi * 16 + l15;
        union { int4 q[2]; int8v v; } ua;
        ua.q[0] = *(const int4*)&As[r * 128 + (((h * 4 + l4) ^ (r & 7)) << 4)];
        ua.q[1] = (int4){0, 0, 0, 0};
        a8[mi] = ua.v;
      }
#pragma unroll
      for (int nj = 0; nj < 4; ++nj) {
        int r = wn * 64 + nj * 16 + l15;
        union { int4 q[2]; int8v v; } ub;
        ub.q[0] = *(const int4*)&Bs[r * 128 + (((h * 4 + l4) ^ (r & 7)) << 4)];
        ub.q[1] = (int4){0, 0, 0, 0};
        b8[nj] = ub.v;
      }
#pragma unroll
      for (int mi = 0; mi < 4; ++mi)
#pragma unroll
        for (int nj = 0; nj < 4; ++nj)
          acc[mi][nj] = MFMA4S(a8[mi], b8[nj], acc[mi][nj]);
    }
    __syncthreads();
  }
  // epilogue: oc<1024 -> qk8[b][p][oc] ; oc>=1024 -> vT8[b][oc-1024][p]
#pragma unroll
  for (int nj = 0; nj < 4; ++nj) {
    int col = n0 + wn * 64 + nj * 16 + l15;
    float bias = bqkv[col];
#pragma unroll
    for (int mi = 0; mi < 4; ++mi) {
      int prow = m0 + wm * 64 + mi * 16 + l4 * 4;
      if (col < 1024) {
#pragma unroll
        for (int rg = 0; rg < 4; ++rg)
          qk8[((size_t)(b * HW_ + prow + rg)) * 1024 + col] =
              f2e4m3(acc[mi][nj][rg] * INV256 + bias);
      } else {
        unsigned pk = pk4_e4m3(acc[mi][nj][0] * INV256 + bias,
                               acc[mi][nj][1] * INV256 + bias,
                               acc[mi][nj][2] * INV256 + bias,
                               acc[mi][nj][3] * INV256 + bias);
        *(unsigned*)&vT8[((size_t)(b * C_ + col - 1024)) * 1024 + prow] = pk;
      }
    }
  }
}

// ---------------- attention, fp8 q/k/v: per block = one batch x 64 q-rows ---
__launch_bounds__(512, 2)
__global__ void attn_kernel(const unsigned char* __restrict__ qk8,
                            const unsigned char* __restrict__ vT8,
                            unsigned short* __restrict__ hb) {
  __shared__ __attribute__((aligned(16))) unsigned short S[64 * 1024];
  unsigned char* P8 = (unsigned char*)S;
  int b  = blockIdx.y;
  int q0 = blockIdx.x * 64;
  int tid = threadIdx.x;
  int w = tid >> 6, lane = tid & 63;
  int l15 = lane & 15, l4 = lane >> 4;
  const unsigned char* qk = qk8 + (size_t)b * HW_ * 1024;

  // ---- phase 1: S = (Q @ K^T) * scale, wave w owns kv-rows [w*128, +128)
  {
    f32x4 acc[4][8];
#pragma unroll
    for (int i = 0; i < 4; ++i)
#pragma unroll
      for (int j = 0; j < 8; ++j) acc[i][j] = (f32x4){0.f, 0.f, 0.f, 0.f};
    for (int kk = 0; kk < 4; ++kk) {
      int cb = kk * 128 + l4 * 32;
      int8v a8[4], b8[8];
#pragma unroll
      for (int mi = 0; mi < 4; ++mi)
        a8[mi] = *(const int8v*)&qk[(size_t)(q0 + mi * 16 + l15) * 1024 + cb];
#pragma unroll
      for (int nj = 0; nj < 8; ++nj)
        b8[nj] = *(const int8v*)&qk[(size_t)(w * 128 + nj * 16 + l15) * 1024 +
                                    512 + cb];
#pragma unroll
      for (int mi = 0; mi < 4; ++mi)
#pragma unroll
        for (int nj = 0; nj < 8; ++nj)
          acc[mi][nj] = MFMA8S(a8[mi], b8[nj], acc[mi][nj]);
    }
    const float scale = 0.044194173824159216f;  // 512^-0.5
#pragma unroll
    for (int mi = 0; mi < 4; ++mi)
#pragma unroll
      for (int nj = 0; nj < 8; ++nj)
#pragma unroll
        for (int rg = 0; rg < 4; ++rg) {
          int m = mi * 16 + l4 * 4 + rg;
          int n = w * 128 + nj * 16 + l15;
          S[m * 1024 + (n ^ ((m & 7) << 3))] = f2bf(acc[mi][nj][rg] * scale);
        }
  }
  __syncthreads();
  // ---- phase 2: softmax, two passes of 32 rows; P8 = fp8(p * 256) in place
  {
#pragma unroll
    for (int rr = 0; rr < 2; ++rr) {
      int row = rr * 32 + (tid >> 4), li = tid & 15;
      int xs = (row & 7) << 3;
      float v[64];
      float mx = -1e30f;
#pragma unroll
      for (int j = 0; j < 64; ++j) {
        v[j] = bf2f(S[row * 1024 + ((li + j * 16) ^ xs)]);
        mx = fmaxf(mx, v[j]);
      }
#pragma unroll
      for (int m = 1; m < 16; m <<= 1) mx = fmaxf(mx, __shfl_xor(mx, m, 64));
      float sum = 0.f;
#pragma unroll
      for (int j = 0; j < 64; ++j) { v[j] = __expf(v[j] - mx); sum += v[j]; }
#pragma unroll
      for (int m = 1; m < 16; m <<= 1) sum += __shfl_xor(sum, m, 64);
      float pi = 256.0f / sum;
      if (rr == 0) __syncthreads();
#pragma unroll
      for (int j = 0; j < 64; ++j)
        P8[row * 1024 + ((j ^ (row & 7)) << 4) + li] = f2e4m3(v[j] * pi);
    }
  }
  __syncthreads();
  // ---- phase 3: O = (P @ V) / 256, wave w owns channels [w*64, +64)
  {
    f32x4 acc3[4][4];
#pragma unroll
    for (int i = 0; i < 4; ++i)
#pragma unroll
      for (int j = 0; j < 4; ++j) acc3[i][j] = (f32x4){0.f, 0.f, 0.f, 0.f};
    const unsigned char* vtb = vT8 + (size_t)b * C_ * 1024;
    for (int kk = 0; kk < 8; ++kk) {
      int8v a8[4], b8[4];
#pragma unroll
      for (int mi = 0; mi < 4; ++mi) {
        int r = mi * 16 + l15;
        int c0 = kk * 8 + l4 * 2;
        union { int4 q[2]; int8v v; } ua;
        ua.q[0] = *(const int4*)&P8[r * 1024 + (((c0 + 0) ^ (r & 7)) << 4)];
        ua.q[1] = *(const int4*)&P8[r * 1024 + (((c0 + 1) ^ (r & 7)) << 4)];
        a8[mi] = ua.v;
      }
#pragma unroll
      for (int nj = 0; nj < 4; ++nj)
        b8[nj] = *(const int8v*)&vtb[(size_t)(w * 64 + nj * 16 + l15) * 1024 +
                                     kk * 128 + l4 * 32];
#pragma unroll
      for (int mi = 0; mi < 4; ++mi)
#pragma unroll
        for (int nj = 0; nj < 4; ++nj)
          acc3[mi][nj] = MFMA8S(a8[mi], b8[nj], acc3[mi][nj]);
    }
#pragma unroll
    for (int mi = 0; mi < 4; ++mi)
#pragma unroll
      for (int nj = 0; nj < 4; ++nj)
#pragma unroll
        for (int rg = 0; rg < 4; ++rg) {
          int p = q0 + mi * 16 + l4 * 4 + rg;
          int c = w * 64 + nj * 16 + l15;
          hb[((size_t)(b * HW_ + p)) * C_ + c] = f2bf(acc3[mi][nj][rg] * INV256);
        }
  }
}

// ---------------- proj 1x1 + bias + residual, C[m=p][n=oc], bf16 ------------
__launch_bounds__(256, 4)
__global__ void proj_res_kernel(const unsigned short* __restrict__ hb,
                                const unsigned short* __restrict__ wp,
                                const float* __restrict__ bproj,
                                const float* __restrict__ x,
                                float* __restrict__ out) {
  __shared__ unsigned short As[128 * 64];  // p-rows   x k
  __shared__ unsigned short Bs[128 * 64];  // oc-rows  x k
  int b   = blockIdx.z;
  int p0  = blockIdx.x * 128;
  int oc0 = blockIdx.y * 128;
  int tid = threadIdx.x;
  int w = tid >> 6, lane = tid & 63;
  int wm = w >> 1, wn = w & 1;
  int l15 = lane & 15, l4 = lane >> 4;
  f32x4 acc[4][4];
#pragma unroll
  for (int i = 0; i < 4; ++i)
#pragma unroll
    for (int j = 0; j < 4; ++j) acc[i][j] = (f32x4){0.f, 0.f, 0.f, 0.f};
  int sr = tid >> 3, sc = tid & 7;
#pragma unroll
  for (int kc = 0; kc < 8; ++kc) {
#pragma unroll
    for (int is = 0; is < 4; ++is) {
      int r  = is * 32 + sr;
      int cg = sc ^ (r & 7);
      GLL16(hb + ((size_t)(b * HW_ + p0 + r)) * 512 + kc * 64 + cg * 8,
            &As[is * 2048 + tid * 8]);
      GLL16(wp + (size_t)(oc0 + r) * 512 + kc * 64 + cg * 8,
            &Bs[is * 2048 + tid * 8]);
    }
    __syncthreads();
#pragma unroll
    for (int kk = 0; kk < 2; ++kk) {
      short8 af[4], bfr[4];
#pragma unroll
      for (int mi = 0; mi < 4; ++mi) {
        int r  = wm * 64 + mi * 16 + l15;
        int ck = kk * 4 + l4;
        af[mi] = *(const short8*)&As[r * 64 + ((ck ^ (r & 7)) << 3)];
      }
#pragma unroll
      for (int nj = 0; nj < 4; ++nj) {
        int r  = wn * 64 + nj * 16 + l15;
        int ck = kk * 4 + l4;
        bfr[nj] = *(const short8*)&Bs[r * 64 + ((ck ^ (r & 7)) << 3)];
      }
#pragma unroll
      for (int mi = 0; mi < 4; ++mi)
#pragma unroll
        for (int nj = 0; nj < 4; ++nj)
          acc[mi][nj] = MFMA16(af[mi], bfr[nj], acc[mi][nj]);
    }
    __syncthreads();
  }
  // epilogue: p = p0+wm*64+mi*16+l4*4 (+rg contiguous), oc = oc0+wn*64+nj*16+l15
#pragma unroll
  for (int nj = 0; nj < 4; ++nj) {
    int oc = oc0 + wn * 64 + nj * 16 + l15;
    float bias = bproj[oc];
#pragma unroll
    for (int mi = 0; mi < 4; ++mi) {
      int p = p0 + wm * 64 + mi * 16 + l4 * 4;
      size_t idx = ((size_t)(b * C_ + oc)) * HW_ + p;
      float4 xv = *(const float4*)&x[idx];
      float4 ov;
      ov.x = acc[mi][nj][0] + bias + xv.x;
      ov.y = acc[mi][nj][1] + bias + xv.y;
      ov.z = acc[mi][nj][2] + bias + xv.z;
      ov.w = acc[mi][nj][3] + bias + xv.w;
      *(float4*)&out[idx] = ov;
    }
  }
}

extern "C" void kernel_launch(void* const* d_in, const int* in_sizes, int n_in,
                              void* d_out, int out_size, void* d_ws,
                              size_t ws_size, hipStream_t stream) {
  const float* x      = (const float*)d_in[0];
  const float* w_qkv  = (const float*)d_in[1];
  const float* b_qkv  = (const float*)d_in[2];
  const float* w_proj = (const float*)d_in[3];
  const float* b_proj = (const float*)d_in[4];

  char* ws = (char*)d_ws;
  unsigned char*  xp4  = (unsigned char*)(ws + 0);           //  4,734,976
  unsigned char*  w2t4 = (unsigned char*)(ws + 4734976);     //  3,538,944
  unsigned short* wpb  = (unsigned short*)(ws + 8273920);    //    524,288
  unsigned char*  qk8  = (unsigned char*)(ws + 8798208);     // 16,777,216
  unsigned char*  vT8  = (unsigned char*)(ws + 25575424);    //  8,388,608
  unsigned short* hb   = (unsigned short*)(ws + 33964032);   // 16,777,216
  float* out = (float*)d_out;

  hipMemsetAsync(xp4, 0, (size_t)B_ * PADP * 256, stream);
  pack_x_kernel<<<dim3(16, 8, 16), 256, 0, stream>>>(x, xp4);
  pack_wqkv_kernel<<<1536, 256, 0, stream>>>(w_qkv, w2t4);
  pack_wproj_kernel<<<1024, 256, 0, stream>>>(w_proj, wpb);
  conv_qkv_kernel<<<dim3(12, 8, 16), 256, 0, stream>>>(xp4, w2t4, b_qkv, qk8, vT8);
  attn_kernel<<<dim3(16, 16), 512, 0, stream>>>(qk8, vT8, hb);
  proj_res_kernel<<<dim3(8, 4, 16), 256, 0, stream>>>(hb, wpb, b_proj, x, out);
}

// Round 18
// 177.791 us; speedup vs baseline: 5.4325x; 5.4325x over previous
//
#include <hip/hip_runtime.h>
#include <stdint.h>

typedef short short8 __attribute__((ext_vector_type(8)));
typedef float f32x4 __attribute__((ext_vector_type(4)));
typedef int int8v __attribute__((ext_vector_type(8)));

#define B_   16
#define C_   512
#define HW_  1024
#define PADP 1156   // 34*34
#define INV256 0.00390625f

__device__ __forceinline__ unsigned short f2bf(float f) {
  union { float f; unsigned u; } v; v.f = f;
  unsigned r = v.u + 0x7FFFu + ((v.u >> 16) & 1u);
  return (unsigned short)(r >> 16);
}
__device__ __forceinline__ float bf2f(unsigned short h) {
  union { unsigned u; float f; } v; v.u = ((unsigned)h) << 16;
  return v.f;
}
// f32 -> OCP e4m3 via HW converter (verified r17: absmax identical to SW RNE)
__device__ __forceinline__ unsigned char f2e4m3(float f) {
  return (unsigned char)(__builtin_amdgcn_cvt_pk_fp8_f32(f, f, 0, false) & 0xFF);
}
// 4x f32 -> packed 4x e4m3 in one u32
__device__ __forceinline__ unsigned pk4_e4m3(float a, float b, float c, float d) {
  int lo = __builtin_amdgcn_cvt_pk_fp8_f32(a, b, 0, false);
  return (unsigned)__builtin_amdgcn_cvt_pk_fp8_f32(c, d, lo, true);
}
// f32 -> fp4 e2m1 nibble, RNE onto {0,.5,1,1.5,2,3,4,6}, saturating
__device__ __forceinline__ unsigned f2e2m1(float f) {
  union { float f; unsigned u; } v; v.f = f;
  unsigned s = (v.u >> 28) & 8u;
  v.u &= 0x7FFFFFFFu;
  float a = v.f;
  unsigned m;
  if (a <= 0.25f) m = 0;
  else if (a < 0.75f) m = 1;
  else if (a <= 1.25f) m = 2;
  else if (a < 1.75f) m = 3;
  else if (a <= 2.5f) m = 4;
  else if (a < 3.5f) m = 5;
  else if (a <= 5.0f) m = 6;
  else m = 7;
  return s | m;
}

#define GLL16(g, l)                                                            \
  __builtin_amdgcn_global_load_lds(                                            \
      (const __attribute__((address_space(1))) void*)(g),                      \
      (__attribute__((address_space(3))) void*)(l), 16, 0, 0)

#define MFMA16(a, b, c) __builtin_amdgcn_mfma_f32_16x16x32_bf16((a), (b), (c), 0, 0, 0)
#define MFMA8S(a, b, c)                                                        \
  __builtin_amdgcn_mfma_scale_f32_16x16x128_f8f6f4(                            \
      (a), (b), (c), 0, 0, 0, 0x7F7F7F7F, 0, 0x7F7F7F7F)
#define MFMA4S(a, b, c)                                                        \
  __builtin_amdgcn_mfma_scale_f32_16x16x128_f8f6f4(                            \
      (a), (b), (c), 4, 4, 0, 0x7F7F7F7F, 0, 0x7F7F7F7F)

// ------ pack x: NCHW f32 -> padded NHWC fp4 nibbles (256 B/pos row) ---------
__global__ void pack_x_kernel(const float* __restrict__ x,
                              unsigned char* __restrict__ xp4) {
  __shared__ float lds[64][69];
  int b  = blockIdx.z;
  int c0 = blockIdx.y * 64;
  int p0 = blockIdx.x * 64;
  int tid = threadIdx.x;
  int pi = tid & 63, cq = tid >> 6;
#pragma unroll
  for (int i = 0; i < 16; ++i) {
    int cl = cq * 16 + i;
    lds[cl][pi] = x[((size_t)(b * C_ + c0 + cl)) * HW_ + p0 + pi];
  }
  __syncthreads();
  int pl = tid >> 2, u = tid & 3;
  int p  = p0 + pl;
  int pp = ((p >> 5) + 1) * 34 + (p & 31) + 1;
  union { unsigned char c[8]; uint2 v; } ob;
#pragma unroll
  for (int j = 0; j < 8; ++j) {
    int cl = u * 16 + 2 * j;
    ob.c[j] = (unsigned char)(f2e2m1(lds[cl][pl]) |
                              (f2e2m1(lds[cl + 1][pl]) << 4));
  }
  *(uint2*)&xp4[((size_t)(b * PADP + pp)) * 256 + (c0 >> 1) + u * 8] = ob.v;
}

// -- pack w_qkv: [oc][ic][t] f32 -> fp4 W2T[oc][k=t*512+ic] x256, 2304 B/row -
__global__ void pack_wqkv_kernel(const float* __restrict__ w,
                                 unsigned char* __restrict__ w2t4) {
  __shared__ float tmp[4608];
  int oc = blockIdx.x;
  for (int s = threadIdx.x; s < 4608; s += 256)
    tmp[s] = w[(size_t)oc * 4608 + s] * 256.f;
  __syncthreads();
  for (int d4 = threadIdx.x; d4 < 576; d4 += 256) {
    uchar4 ob;
#pragma unroll
    for (int i = 0; i < 4; ++i) {
      int k0 = (d4 * 4 + i) * 2;           // even k; pair within same tap
      int t = k0 >> 9, ic = k0 & 511;
      unsigned lo = f2e2m1(tmp[ic * 9 + t]);
      unsigned hi = f2e2m1(tmp[(ic + 1) * 9 + t]);
      ((unsigned char*)&ob)[i] = (unsigned char)(lo | (hi << 4));
    }
    *(uchar4*)&w2t4[(size_t)oc * 2304 + d4 * 4] = ob;
  }
}

// ---------------- pack w_proj: f32 -> bf16 ----------------------------------
__global__ void pack_wproj_kernel(const float* __restrict__ w,
                                  unsigned short* __restrict__ wp) {
  int i = blockIdx.x * 256 + threadIdx.x;
  wp[i] = f2bf(w[i]);
}

// ------- conv3x3 implicit GEMM, MX-fp4, BK=256 els (128 B rows), 2-phase ----
// Runtime st loop (r17 full unroll blew the I-cache: FETCH 25 MB -> 1.5 GB).
__launch_bounds__(256, 4)
__global__ void conv_qkv_kernel(const unsigned char* __restrict__ xp4,
                                const unsigned char* __restrict__ w2t4,
                                const float* __restrict__ bqkv,
                                unsigned char* __restrict__ qk8,
                                unsigned char* __restrict__ vT8) {
  __shared__ __attribute__((aligned(16))) unsigned char As[128 * 128];
  __shared__ __attribute__((aligned(16))) unsigned char Bs[128 * 128];
  int b  = blockIdx.z;
  int m0 = blockIdx.y * 128;
  int n0 = blockIdx.x * 128;
  int tid = threadIdx.x;
  int w = tid >> 6, lane = tid & 63;
  int wm = w >> 1, wn = w & 1;
  int l15 = lane & 15, l4 = lane >> 4;
  f32x4 acc[4][4];
#pragma unroll
  for (int i = 0; i < 4; ++i)
#pragma unroll
    for (int j = 0; j < 4; ++j) acc[i][j] = (f32x4){0.f, 0.f, 0.f, 0.f};

  int sr = tid >> 3;  // staging row within 32-row group (8 x 16B = 128 B row)
  int sc = tid & 7;

  for (int st = 0; st < 18; ++st) {
    int tap  = st >> 1;
    int half = st & 1;  // which 256-element half of the tap's 512 channels
    int off  = (tap / 3 - 1) * 34 + (tap % 3) - 1;
#pragma unroll
    for (int is = 0; is < 4; ++is) {
      int r  = is * 32 + sr;
      int p  = m0 + r;
      int pp = ((p >> 5) + 1) * 34 + (p & 31) + 1 + off;
      int cg = sc ^ (r & 7);
      GLL16(xp4 + ((size_t)(b * PADP + pp)) * 256 + half * 128 + cg * 16,
            &As[is * 4096 + tid * 16]);
    }
#pragma unroll
    for (int is = 0; is < 4; ++is) {
      int r  = is * 32 + sr;
      int cg = sc ^ (r & 7);
      GLL16(w2t4 + (size_t)(n0 + r) * 2304 + st * 128 + cg * 16,
            &Bs[is * 4096 + tid * 16]);
    }
    __syncthreads();
#pragma unroll
    for (int h = 0; h < 2; ++h) {
      int8v a8[4], b8[4];
#pragma unroll
      for (int mi = 0; mi < 4; ++mi) {
        int r = wm * 64 + mi * 16 + l15;
        union { int4 q[2]; int8v v; } ua;
        ua.q[0] = *(const int4*)&As[r * 128 + (((h * 4 + l4) ^ (r & 7)) << 4)];
        ua.q[1] = (int4){0, 0, 0, 0};
        a8[mi] = ua.v;
      }
#pragma unroll
      for (int nj = 0; nj < 4; ++nj) {
        int r = wn * 64 + nj * 16 + l15;
        union { int4 q[2]; int8v v; } ub;
        ub.q[0] = *(const int4*)&Bs[r * 128 + (((h * 4 + l4) ^ (r & 7)) << 4)];
        ub.q[1] = (int4){0, 0, 0, 0};
        b8[nj] = ub.v;
      }
#pragma unroll
      for (int mi = 0; mi < 4; ++mi)
#pragma unroll
        for (int nj = 0; nj < 4; ++nj)
          acc[mi][nj] = MFMA4S(a8[mi], b8[nj], acc[mi][nj]);
    }
    __syncthreads();
  }
  // epilogue: oc<1024 -> qk8[b][p][oc] ; oc>=1024 -> vT8[b][oc-1024][p]
#pragma unroll
  for (int nj = 0; nj < 4; ++nj) {
    int col = n0 + wn * 64 + nj * 16 + l15;
    float bias = bqkv[col];
#pragma unroll
    for (int mi = 0; mi < 4; ++mi) {
      int prow = m0 + wm * 64 + mi * 16 + l4 * 4;
      if (col < 1024) {
#pragma unroll
        for (int rg = 0; rg < 4; ++rg)
          qk8[((size_t)(b * HW_ + prow + rg)) * 1024 + col] =
              f2e4m3(acc[mi][nj][rg] * INV256 + bias);
      } else {
        unsigned pk = pk4_e4m3(acc[mi][nj][0] * INV256 + bias,
                               acc[mi][nj][1] * INV256 + bias,
                               acc[mi][nj][2] * INV256 + bias,
                               acc[mi][nj][3] * INV256 + bias);
        *(unsigned*)&vT8[((size_t)(b * C_ + col - 1024)) * 1024 + prow] = pk;
      }
    }
  }
}

// ---------------- attention, fp8 q/k/v: per block = one batch x 64 q-rows ---
__launch_bounds__(512, 2)
__global__ void attn_kernel(const unsigned char* __restrict__ qk8,
                            const unsigned char* __restrict__ vT8,
                            unsigned short* __restrict__ hb) {
  __shared__ __attribute__((aligned(16))) unsigned short S[64 * 1024];
  unsigned char* P8 = (unsigned char*)S;
  int b  = blockIdx.y;
  int q0 = blockIdx.x * 64;
  int tid = threadIdx.x;
  int w = tid >> 6, lane = tid & 63;
  int l15 = lane & 15, l4 = lane >> 4;
  const unsigned char* qk = qk8 + (size_t)b * HW_ * 1024;

  // ---- phase 1: S = (Q @ K^T) * scale, wave w owns kv-rows [w*128, +128)
  {
    f32x4 acc[4][8];
#pragma unroll
    for (int i = 0; i < 4; ++i)
#pragma unroll
      for (int j = 0; j < 8; ++j) acc[i][j] = (f32x4){0.f, 0.f, 0.f, 0.f};
    for (int kk = 0; kk < 4; ++kk) {
      int cb = kk * 128 + l4 * 32;
      int8v a8[4], b8[8];
#pragma unroll
      for (int mi = 0; mi < 4; ++mi)
        a8[mi] = *(const int8v*)&qk[(size_t)(q0 + mi * 16 + l15) * 1024 + cb];
#pragma unroll
      for (int nj = 0; nj < 8; ++nj)
        b8[nj] = *(const int8v*)&qk[(size_t)(w * 128 + nj * 16 + l15) * 1024 +
                                    512 + cb];
#pragma unroll
      for (int mi = 0; mi < 4; ++mi)
#pragma unroll
        for (int nj = 0; nj < 8; ++nj)
          acc[mi][nj] = MFMA8S(a8[mi], b8[nj], acc[mi][nj]);
    }
    const float scale = 0.044194173824159216f;  // 512^-0.5
#pragma unroll
    for (int mi = 0; mi < 4; ++mi)
#pragma unroll
      for (int nj = 0; nj < 8; ++nj)
#pragma unroll
        for (int rg = 0; rg < 4; ++rg) {
          int m = mi * 16 + l4 * 4 + rg;
          int n = w * 128 + nj * 16 + l15;
          S[m * 1024 + (n ^ ((m & 7) << 3))] = f2bf(acc[mi][nj][rg] * scale);
        }
  }
  __syncthreads();
  // ---- phase 2: softmax, two passes of 32 rows; P8 = fp8(p * 256) in place
  {
#pragma unroll
    for (int rr = 0; rr < 2; ++rr) {
      int row = rr * 32 + (tid >> 4), li = tid & 15;
      int xs = (row & 7) << 3;
      float v[64];
      float mx = -1e30f;
#pragma unroll
      for (int j = 0; j < 64; ++j) {
        v[j] = bf2f(S[row * 1024 + ((li + j * 16) ^ xs)]);
        mx = fmaxf(mx, v[j]);
      }
#pragma unroll
      for (int m = 1; m < 16; m <<= 1) mx = fmaxf(mx, __shfl_xor(mx, m, 64));
      float sum = 0.f;
#pragma unroll
      for (int j = 0; j < 64; ++j) { v[j] = __expf(v[j] - mx); sum += v[j]; }
#pragma unroll
      for (int m = 1; m < 16; m <<= 1) sum += __shfl_xor(sum, m, 64);
      float pi = 256.0f / sum;
      if (rr == 0) __syncthreads();
#pragma unroll
      for (int j = 0; j < 64; ++j)
        P8[row * 1024 + ((j ^ (row & 7)) << 4) + li] = f2e4m3(v[j] * pi);
    }
  }
  __syncthreads();
  // ---- phase 3: O = (P @ V) / 256, wave w owns channels [w*64, +64)
  {
    f32x4 acc3[4][4];
#pragma unroll
    for (int i = 0; i < 4; ++i)
#pragma unroll
      for (int j = 0; j < 4; ++j) acc3[i][j] = (f32x4){0.f, 0.f, 0.f, 0.f};
    const unsigned char* vtb = vT8 + (size_t)b * C_ * 1024;
    for (int kk = 0; kk < 8; ++kk) {
      int8v a8[4], b8[4];
#pragma unroll
      for (int mi = 0; mi < 4; ++mi) {
        int r = mi * 16 + l15;
        int c0 = kk * 8 + l4 * 2;
        union { int4 q[2]; int8v v; } ua;
        ua.q[0] = *(const int4*)&P8[r * 1024 + (((c0 + 0) ^ (r & 7)) << 4)];
        ua.q[1] = *(const int4*)&P8[r * 1024 + (((c0 + 1) ^ (r & 7)) << 4)];
        a8[mi] = ua.v;
      }
#pragma unroll
      for (int nj = 0; nj < 4; ++nj)
        b8[nj] = *(const int8v*)&vtb[(size_t)(w * 64 + nj * 16 + l15) * 1024 +
                                     kk * 128 + l4 * 32];
#pragma unroll
      for (int mi = 0; mi < 4; ++mi)
#pragma unroll
        for (int nj = 0; nj < 4; ++nj)
          acc3[mi][nj] = MFMA8S(a8[mi], b8[nj], acc3[mi][nj]);
    }
#pragma unroll
    for (int mi = 0; mi < 4; ++mi)
#pragma unroll
      for (int nj = 0; nj < 4; ++nj)
#pragma unroll
        for (int rg = 0; rg < 4; ++rg) {
          int p = q0 + mi * 16 + l4 * 4 + rg;
          int c = w * 64 + nj * 16 + l15;
          hb[((size_t)(b * HW_ + p)) * C_ + c] = f2bf(acc3[mi][nj][rg] * INV256);
        }
  }
}

// ---------------- proj 1x1 + bias + residual, C[m=p][n=oc], bf16 ------------
__launch_bounds__(256, 4)
__global__ void proj_res_kernel(const unsigned short* __restrict__ hb,
                                const unsigned short* __restrict__ wp,
                                const float* __restrict__ bproj,
                                const float* __restrict__ x,
                                float* __restrict__ out) {
  __shared__ unsigned short As[128 * 64];  // p-rows   x k
  __shared__ unsigned short Bs[128 * 64];  // oc-rows  x k
  int b   = blockIdx.z;
  int p0  = blockIdx.x * 128;
  int oc0 = blockIdx.y * 128;
  int tid = threadIdx.x;
  int w = tid >> 6, lane = tid & 63;
  int wm = w >> 1, wn = w & 1;
  int l15 = lane & 15, l4 = lane >> 4;
  f32x4 acc[4][4];
#pragma unroll
  for (int i = 0; i < 4; ++i)
#pragma unroll
    for (int j = 0; j < 4; ++j) acc[i][j] = (f32x4){0.f, 0.f, 0.f, 0.f};
  int sr = tid >> 3, sc = tid & 7;
  for (int kc = 0; kc < 8; ++kc) {
#pragma unroll
    for (int is = 0; is < 4; ++is) {
      int r  = is * 32 + sr;
      int cg = sc ^ (r & 7);
      GLL16(hb + ((size_t)(b * HW_ + p0 + r)) * 512 + kc * 64 + cg * 8,
            &As[is * 2048 + tid * 8]);
      GLL16(wp + (size_t)(oc0 + r) * 512 + kc * 64 + cg * 8,
            &Bs[is * 2048 + tid * 8]);
    }
    __syncthreads();
#pragma unroll
    for (int kk = 0; kk < 2; ++kk) {
      short8 af[4], bfr[4];
#pragma unroll
      for (int mi = 0; mi < 4; ++mi) {
        int r  = wm * 64 + mi * 16 + l15;
        int ck = kk * 4 + l4;
        af[mi] = *(const short8*)&As[r * 64 + ((ck ^ (r & 7)) << 3)];
      }
#pragma unroll
      for (int nj = 0; nj < 4; ++nj) {
        int r  = wn * 64 + nj * 16 + l15;
        int ck = kk * 4 + l4;
        bfr[nj] = *(const short8*)&Bs[r * 64 + ((ck ^ (r & 7)) << 3)];
      }
#pragma unroll
      for (int mi = 0; mi < 4; ++mi)
#pragma unroll
        for (int nj = 0; nj < 4; ++nj)
          acc[mi][nj] = MFMA16(af[mi], bfr[nj], acc[mi][nj]);
    }
    __syncthreads();
  }
  // epilogue: p = p0+wm*64+mi*16+l4*4 (+rg contiguous), oc = oc0+wn*64+nj*16+l15
#pragma unroll
  for (int nj = 0; nj < 4; ++nj) {
    int oc = oc0 + wn * 64 + nj * 16 + l15;
    float bias = bproj[oc];
#pragma unroll
    for (int mi = 0; mi < 4; ++mi) {
      int p = p0 + wm * 64 + mi * 16 + l4 * 4;
      size_t idx = ((size_t)(b * C_ + oc)) * HW_ + p;
      float4 xv = *(const float4*)&x[idx];
      float4 ov;
      ov.x = acc[mi][nj][0] + bias + xv.x;
      ov.y = acc[mi][nj][1] + bias + xv.y;
      ov.z = acc[mi][nj][2] + bias + xv.z;
      ov.w = acc[mi][nj][3] + bias + xv.w;
      *(float4*)&out[idx] = ov;
    }
  }
}

extern "C" void kernel_launch(void* const* d_in, const int* in_sizes, int n_in,
                              void* d_out, int out_size, void* d_ws,
                              size_t ws_size, hipStream_t stream) {
  const float* x      = (const float*)d_in[0];
  const float* w_qkv  = (const float*)d_in[1];
  const float* b_qkv  = (const float*)d_in[2];
  const float* w_proj = (const float*)d_in[3];
  const float* b_proj = (const float*)d_in[4];

  char* ws = (char*)d_ws;
  unsigned char*  xp4  = (unsigned char*)(ws + 0);           //  4,734,976
  unsigned char*  w2t4 = (unsigned char*)(ws + 4734976);     //  3,538,944
  unsigned short* wpb  = (unsigned short*)(ws + 8273920);    //    524,288
  unsigned char*  qk8  = (unsigned char*)(ws + 8798208);     // 16,777,216
  unsigned char*  vT8  = (unsigned char*)(ws + 25575424);    //  8,388,608
  unsigned short* hb   = (unsigned short*)(ws + 33964032);   // 16,777,216
  float* out = (float*)d_out;

  hipMemsetAsync(xp4, 0, (size_t)B_ * PADP * 256, stream);
  pack_x_kernel<<<dim3(16, 8, 16), 256, 0, stream>>>(x, xp4);
  pack_wqkv_kernel<<<1536, 256, 0, stream>>>(w_qkv, w2t4);
  pack_wproj_kernel<<<1024, 256, 0, stream>>>(w_proj, wpb);
  conv_qkv_kernel<<<dim3(12, 8, 16), 256, 0, stream>>>(xp4, w2t4, b_qkv, qk8, vT8);
  attn_kernel<<<dim3(16, 16), 512, 0, stream>>>(qk8, vT8, hb);
  proj_res_kernel<<<dim3(8, 4, 16), 256, 0, stream>>>(hb, wpb, b_proj, x, out);
}

// Round 19
// 176.155 us; speedup vs baseline: 5.4829x; 1.0093x over previous
//
#include <hip/hip_runtime.h>
#include <stdint.h>

typedef short short8 __attribute__((ext_vector_type(8)));
typedef float f32x4 __attribute__((ext_vector_type(4)));
typedef int int8v __attribute__((ext_vector_type(8)));

#define B_   16
#define C_   512
#define HW_  1024
#define PADP 1156   // 34*34
#define INV256 0.00390625f

__device__ __forceinline__ unsigned short f2bf(float f) {
  union { float f; unsigned u; } v; v.f = f;
  unsigned r = v.u + 0x7FFFu + ((v.u >> 16) & 1u);
  return (unsigned short)(r >> 16);
}
__device__ __forceinline__ float bf2f(unsigned short h) {
  union { unsigned u; float f; } v; v.u = ((unsigned)h) << 16;
  return v.f;
}
// f32 -> OCP e4m3 via HW converter (verified r17/r18: matches SW RNE)
__device__ __forceinline__ unsigned char f2e4m3(float f) {
  return (unsigned char)(__builtin_amdgcn_cvt_pk_fp8_f32(f, f, 0, false) & 0xFF);
}
// 4x f32 -> packed 4x e4m3 in one u32
__device__ __forceinline__ unsigned pk4_e4m3(float a, float b, float c, float d) {
  int lo = __builtin_amdgcn_cvt_pk_fp8_f32(a, b, 0, false);
  return (unsigned)__builtin_amdgcn_cvt_pk_fp8_f32(c, d, lo, true);
}
// f32 -> fp4 e2m1 nibble, RNE onto {0,.5,1,1.5,2,3,4,6}, saturating
__device__ __forceinline__ unsigned f2e2m1(float f) {
  union { float f; unsigned u; } v; v.f = f;
  unsigned s = (v.u >> 28) & 8u;
  v.u &= 0x7FFFFFFFu;
  float a = v.f;
  unsigned m;
  if (a <= 0.25f) m = 0;
  else if (a < 0.75f) m = 1;
  else if (a <= 1.25f) m = 2;
  else if (a < 1.75f) m = 3;
  else if (a <= 2.5f) m = 4;
  else if (a < 3.5f) m = 5;
  else if (a <= 5.0f) m = 6;
  else m = 7;
  return s | m;
}

#define GLL16(g, l)                                                            \
  __builtin_amdgcn_global_load_lds(                                            \
      (const __attribute__((address_space(1))) void*)(g),                      \
      (__attribute__((address_space(3))) void*)(l), 16, 0, 0)

#define MFMA16(a, b, c) __builtin_amdgcn_mfma_f32_16x16x32_bf16((a), (b), (c), 0, 0, 0)
#define MFMA8S(a, b, c)                                                        \
  __builtin_amdgcn_mfma_scale_f32_16x16x128_f8f6f4(                            \
      (a), (b), (c), 0, 0, 0, 0x7F7F7F7F, 0, 0x7F7F7F7F)
#define MFMA4S(a, b, c)                                                        \
  __builtin_amdgcn_mfma_scale_f32_16x16x128_f8f6f4(                            \
      (a), (b), (c), 4, 4, 0, 0x7F7F7F7F, 0, 0x7F7F7F7F)

// ---- zero only the pad ring of xp4 (132 positions x 256 B per batch) -------
__global__ void zero_border_kernel(unsigned char* __restrict__ xp4) {
  int gid = blockIdx.x * 256 + threadIdx.x;   // 132 blocks x 256 = 33792
  int j16 = gid & 15;
  int pos = gid >> 4;          // 0..2111
  int b   = pos / 132;
  int k   = pos % 132;
  int r, c;
  if (k < 34)       { r = 0;            c = k; }
  else if (k < 68)  { r = 33;           c = k - 34; }
  else if (k < 100) { r = 1 + (k - 68); c = 0; }
  else              { r = 1 + (k - 100); c = 33; }
  int pp = r * 34 + c;
  uint4 z = {0, 0, 0, 0};
  *(uint4*)&xp4[((size_t)(b * PADP + pp)) * 256 + j16 * 16] = z;
}

// ------ pack x: NCHW f32 -> padded NHWC fp4 nibbles (256 B/pos row) ---------
__global__ void pack_x_kernel(const float* __restrict__ x,
                              unsigned char* __restrict__ xp4) {
  __shared__ float lds[64][69];
  int b  = blockIdx.z;
  int c0 = blockIdx.y * 64;
  int p0 = blockIdx.x * 64;
  int tid = threadIdx.x;
  int pi = tid & 63, cq = tid >> 6;
#pragma unroll
  for (int i = 0; i < 16; ++i) {
    int cl = cq * 16 + i;
    lds[cl][pi] = x[((size_t)(b * C_ + c0 + cl)) * HW_ + p0 + pi];
  }
  __syncthreads();
  int pl = tid >> 2, u = tid & 3;
  int p  = p0 + pl;
  int pp = ((p >> 5) + 1) * 34 + (p & 31) + 1;
  union { unsigned char c[8]; uint2 v; } ob;
#pragma unroll
  for (int j = 0; j < 8; ++j) {
    int cl = u * 16 + 2 * j;
    ob.c[j] = (unsigned char)(f2e2m1(lds[cl][pl]) |
                              (f2e2m1(lds[cl + 1][pl]) << 4));
  }
  *(uint2*)&xp4[((size_t)(b * PADP + pp)) * 256 + (c0 >> 1) + u * 8] = ob.v;
}

// -- pack w_qkv: [oc][ic][t] f32 -> fp4 W2T[oc][k=t*512+ic] x256, 2304 B/row -
__global__ void pack_wqkv_kernel(const float* __restrict__ w,
                                 unsigned char* __restrict__ w2t4) {
  __shared__ float tmp[4608];
  int oc = blockIdx.x;
  for (int s = threadIdx.x; s < 4608; s += 256)
    tmp[s] = w[(size_t)oc * 4608 + s] * 256.f;
  __syncthreads();
  for (int d4 = threadIdx.x; d4 < 576; d4 += 256) {
    uchar4 ob;
#pragma unroll
    for (int i = 0; i < 4; ++i) {
      int k0 = (d4 * 4 + i) * 2;           // even k; pair within same tap
      int t = k0 >> 9, ic = k0 & 511;
      unsigned lo = f2e2m1(tmp[ic * 9 + t]);
      unsigned hi = f2e2m1(tmp[(ic + 1) * 9 + t]);
      ((unsigned char*)&ob)[i] = (unsigned char)(lo | (hi << 4));
    }
    *(uchar4*)&w2t4[(size_t)oc * 2304 + d4 * 4] = ob;
  }
}

// ---------------- pack w_proj: f32 -> bf16 ----------------------------------
__global__ void pack_wproj_kernel(const float* __restrict__ w,
                                  unsigned short* __restrict__ wp) {
  int i = blockIdx.x * 256 + threadIdx.x;
  wp[i] = f2bf(w[i]);
}

// ------- conv3x3 implicit GEMM, MX-fp4, BK=256 els (128 B rows), 2-phase ----
__launch_bounds__(256, 4)
__global__ void conv_qkv_kernel(const unsigned char* __restrict__ xp4,
                                const unsigned char* __restrict__ w2t4,
                                const float* __restrict__ bqkv,
                                unsigned char* __restrict__ qk8,
                                unsigned char* __restrict__ vT8) {
  __shared__ __attribute__((aligned(16))) unsigned char As[128 * 128];
  __shared__ __attribute__((aligned(16))) unsigned char Bs[128 * 128];
  int b  = blockIdx.z;
  int m0 = blockIdx.y * 128;
  int n0 = blockIdx.x * 128;
  int tid = threadIdx.x;
  int w = tid >> 6, lane = tid & 63;
  int wm = w >> 1, wn = w & 1;
  int l15 = lane & 15, l4 = lane >> 4;
  f32x4 acc[4][4];
#pragma unroll
  for (int i = 0; i < 4; ++i)
#pragma unroll
    for (int j = 0; j < 4; ++j) acc[i][j] = (f32x4){0.f, 0.f, 0.f, 0.f};

  int sr = tid >> 3;  // staging row within 32-row group (8 x 16B = 128 B row)
  int sc = tid & 7;

  for (int st = 0; st < 18; ++st) {
    int tap  = st >> 1;
    int half = st & 1;  // which 256-element half of the tap's 512 channels
    int off  = (tap / 3 - 1) * 34 + (tap % 3) - 1;
#pragma unroll
    for (int is = 0; is < 4; ++is) {
      int r  = is * 32 + sr;
      int p  = m0 + r;
      int pp = ((p >> 5) + 1) * 34 + (p & 31) + 1 + off;
      int cg = sc ^ (r & 7);
      GLL16(xp4 + ((size_t)(b * PADP + pp)) * 256 + half * 128 + cg * 16,
            &As[is * 4096 + tid * 16]);
    }
#pragma unroll
    for (int is = 0; is < 4; ++is) {
      int r  = is * 32 + sr;
      int cg = sc ^ (r & 7);
      GLL16(w2t4 + (size_t)(n0 + r) * 2304 + st * 128 + cg * 16,
            &Bs[is * 4096 + tid * 16]);
    }
    __syncthreads();
#pragma unroll
    for (int h = 0; h < 2; ++h) {
      int8v a8[4], b8[4];
#pragma unroll
      for (int mi = 0; mi < 4; ++mi) {
        int r = wm * 64 + mi * 16 + l15;
        union { int4 q[2]; int8v v; } ua;
        ua.q[0] = *(const int4*)&As[r * 128 + (((h * 4 + l4) ^ (r & 7)) << 4)];
        ua.q[1] = (int4){0, 0, 0, 0};
        a8[mi] = ua.v;
      }
#pragma unroll
      for (int nj = 0; nj < 4; ++nj) {
        int r = wn * 64 + nj * 16 + l15;
        union { int4 q[2]; int8v v; } ub;
        ub.q[0] = *(const int4*)&Bs[r * 128 + (((h * 4 + l4) ^ (r & 7)) << 4)];
        ub.q[1] = (int4){0, 0, 0, 0};
        b8[nj] = ub.v;
      }
#pragma unroll
      for (int mi = 0; mi < 4; ++mi)
#pragma unroll
        for (int nj = 0; nj < 4; ++nj)
          acc[mi][nj] = MFMA4S(a8[mi], b8[nj], acc[mi][nj]);
    }
    __syncthreads();
  }
  // epilogue: oc<1024 -> qk8[b][p][oc] ; oc>=1024 -> vT8[b][oc-1024][p]
#pragma unroll
  for (int nj = 0; nj < 4; ++nj) {
    int col = n0 + wn * 64 + nj * 16 + l15;
    float bias = bqkv[col];
#pragma unroll
    for (int mi = 0; mi < 4; ++mi) {
      int prow = m0 + wm * 64 + mi * 16 + l4 * 4;
      if (col < 1024) {
#pragma unroll
        for (int rg = 0; rg < 4; ++rg)
          qk8[((size_t)(b * HW_ + prow + rg)) * 1024 + col] =
              f2e4m3(acc[mi][nj][rg] * INV256 + bias);
      } else {
        unsigned pk = pk4_e4m3(acc[mi][nj][0] * INV256 + bias,
                               acc[mi][nj][1] * INV256 + bias,
                               acc[mi][nj][2] * INV256 + bias,
                               acc[mi][nj][3] * INV256 + bias);
        *(unsigned*)&vT8[((size_t)(b * C_ + col - 1024)) * 1024 + prow] = pk;
      }
    }
  }
}

// ---------------- attention, fp8 q/k/v: per block = one batch x 64 q-rows ---
// XCD batch affinity: bid&7 = XCD; XCD k owns batches {2k,2k+1}; per-XCD
// K/V working set = 2 MB < 4 MB L2. Bijective remap, perf-only.
__launch_bounds__(512, 2)
__global__ void attn_kernel(const unsigned char* __restrict__ qk8,
                            const unsigned char* __restrict__ vT8,
                            unsigned short* __restrict__ hb) {
  __shared__ __attribute__((aligned(16))) unsigned short S[64 * 1024];
  unsigned char* P8 = (unsigned char*)S;
  int bid = blockIdx.x;
  int b   = (bid & 7) * 2 + ((bid >> 3) & 1);
  int q0  = (bid >> 4) * 64;
  int tid = threadIdx.x;
  int w = tid >> 6, lane = tid & 63;
  int l15 = lane & 15, l4 = lane >> 4;
  const unsigned char* qk = qk8 + (size_t)b * HW_ * 1024;

  // ---- phase 1: S = (Q @ K^T) * scale, wave w owns kv-rows [w*128, +128)
  {
    f32x4 acc[4][8];
#pragma unroll
    for (int i = 0; i < 4; ++i)
#pragma unroll
      for (int j = 0; j < 8; ++j) acc[i][j] = (f32x4){0.f, 0.f, 0.f, 0.f};
    for (int kk = 0; kk < 4; ++kk) {
      int cb = kk * 128 + l4 * 32;
      int8v a8[4], b8[8];
#pragma unroll
      for (int mi = 0; mi < 4; ++mi)
        a8[mi] = *(const int8v*)&qk[(size_t)(q0 + mi * 16 + l15) * 1024 + cb];
#pragma unroll
      for (int nj = 0; nj < 8; ++nj)
        b8[nj] = *(const int8v*)&qk[(size_t)(w * 128 + nj * 16 + l15) * 1024 +
                                    512 + cb];
#pragma unroll
      for (int mi = 0; mi < 4; ++mi)
#pragma unroll
        for (int nj = 0; nj < 8; ++nj)
          acc[mi][nj] = MFMA8S(a8[mi], b8[nj], acc[mi][nj]);
    }
    const float scale = 0.044194173824159216f;  // 512^-0.5
#pragma unroll
    for (int mi = 0; mi < 4; ++mi)
#pragma unroll
      for (int nj = 0; nj < 8; ++nj)
#pragma unroll
        for (int rg = 0; rg < 4; ++rg) {
          int m = mi * 16 + l4 * 4 + rg;
          int n = w * 128 + nj * 16 + l15;
          S[m * 1024 + (n ^ ((m & 7) << 3))] = f2bf(acc[mi][nj][rg] * scale);
        }
  }
  __syncthreads();
  // ---- phase 2: softmax, two passes of 32 rows; P8 = fp8(p * 256) in place
  {
#pragma unroll
    for (int rr = 0; rr < 2; ++rr) {
      int row = rr * 32 + (tid >> 4), li = tid & 15;
      int xs = (row & 7) << 3;
      float v[64];
      float mx = -1e30f;
#pragma unroll
      for (int j = 0; j < 64; ++j) {
        v[j] = bf2f(S[row * 1024 + ((li + j * 16) ^ xs)]);
        mx = fmaxf(mx, v[j]);
      }
#pragma unroll
      for (int m = 1; m < 16; m <<= 1) mx = fmaxf(mx, __shfl_xor(mx, m, 64));
      float sum = 0.f;
#pragma unroll
      for (int j = 0; j < 64; ++j) { v[j] = __expf(v[j] - mx); sum += v[j]; }
#pragma unroll
      for (int m = 1; m < 16; m <<= 1) sum += __shfl_xor(sum, m, 64);
      float pi = 256.0f / sum;
      if (rr == 0) __syncthreads();
#pragma unroll
      for (int j = 0; j < 64; ++j)
        P8[row * 1024 + ((j ^ (row & 7)) << 4) + li] = f2e4m3(v[j] * pi);
    }
  }
  __syncthreads();
  // ---- phase 3: O = (P @ V) / 256, wave w owns channels [w*64, +64)
  {
    f32x4 acc3[4][4];
#pragma unroll
    for (int i = 0; i < 4; ++i)
#pragma unroll
      for (int j = 0; j < 4; ++j) acc3[i][j] = (f32x4){0.f, 0.f, 0.f, 0.f};
    const unsigned char* vtb = vT8 + (size_t)b * C_ * 1024;
    for (int kk = 0; kk < 8; ++kk) {
      int8v a8[4], b8[4];
#pragma unroll
      for (int mi = 0; mi < 4; ++mi) {
        int r = mi * 16 + l15;
        int c0 = kk * 8 + l4 * 2;
        union { int4 q[2]; int8v v; } ua;
        ua.q[0] = *(const int4*)&P8[r * 1024 + (((c0 + 0) ^ (r & 7)) << 4)];
        ua.q[1] = *(const int4*)&P8[r * 1024 + (((c0 + 1) ^ (r & 7)) << 4)];
        a8[mi] = ua.v;
      }
#pragma unroll
      for (int nj = 0; nj < 4; ++nj)
        b8[nj] = *(const int8v*)&vtb[(size_t)(w * 64 + nj * 16 + l15) * 1024 +
                                     kk * 128 + l4 * 32];
#pragma unroll
      for (int mi = 0; mi < 4; ++mi)
#pragma unroll
        for (int nj = 0; nj < 4; ++nj)
          acc3[mi][nj] = MFMA8S(a8[mi], b8[nj], acc3[mi][nj]);
    }
#pragma unroll
    for (int mi = 0; mi < 4; ++mi)
#pragma unroll
      for (int nj = 0; nj < 4; ++nj)
#pragma unroll
        for (int rg = 0; rg < 4; ++rg) {
          int p = q0 + mi * 16 + l4 * 4 + rg;
          int c = w * 64 + nj * 16 + l15;
          hb[((size_t)(b * HW_ + p)) * C_ + c] = f2bf(acc3[mi][nj][rg] * INV256);
        }
  }
}

// ---------------- proj 1x1 + bias + residual, C[m=p][n=oc], bf16 ------------
__launch_bounds__(256, 4)
__global__ void proj_res_kernel(const unsigned short* __restrict__ hb,
                                const unsigned short* __restrict__ wp,
                                const float* __restrict__ bproj,
                                const float* __restrict__ x,
                                float* __restrict__ out) {
  __shared__ unsigned short As[128 * 64];  // p-rows   x k
  __shared__ unsigned short Bs[128 * 64];  // oc-rows  x k
  int b   = blockIdx.z;
  int p0  = blockIdx.x * 128;
  int oc0 = blockIdx.y * 128;
  int tid = threadIdx.x;
  int w = tid >> 6, lane = tid & 63;
  int wm = w >> 1, wn = w & 1;
  int l15 = lane & 15, l4 = lane >> 4;
  f32x4 acc[4][4];
#pragma unroll
  for (int i = 0; i < 4; ++i)
#pragma unroll
    for (int j = 0; j < 4; ++j) acc[i][j] = (f32x4){0.f, 0.f, 0.f, 0.f};
  int sr = tid >> 3, sc = tid & 7;
  for (int kc = 0; kc < 8; ++kc) {
#pragma unroll
    for (int is = 0; is < 4; ++is) {
      int r  = is * 32 + sr;
      int cg = sc ^ (r & 7);
      GLL16(hb + ((size_t)(b * HW_ + p0 + r)) * 512 + kc * 64 + cg * 8,
            &As[is * 2048 + tid * 8]);
      GLL16(wp + (size_t)(oc0 + r) * 512 + kc * 64 + cg * 8,
            &Bs[is * 2048 + tid * 8]);
    }
    __syncthreads();
#pragma unroll
    for (int kk = 0; kk < 2; ++kk) {
      short8 af[4], bfr[4];
#pragma unroll
      for (int mi = 0; mi < 4; ++mi) {
        int r  = wm * 64 + mi * 16 + l15;
        int ck = kk * 4 + l4;
        af[mi] = *(const short8*)&As[r * 64 + ((ck ^ (r & 7)) << 3)];
      }
#pragma unroll
      for (int nj = 0; nj < 4; ++nj) {
        int r  = wn * 64 + nj * 16 + l15;
        int ck = kk * 4 + l4;
        bfr[nj] = *(const short8*)&Bs[r * 64 + ((ck ^ (r & 7)) << 3)];
      }
#pragma unroll
      for (int mi = 0; mi < 4; ++mi)
#pragma unroll
        for (int nj = 0; nj < 4; ++nj)
          acc[mi][nj] = MFMA16(af[mi], bfr[nj], acc[mi][nj]);
    }
    __syncthreads();
  }
  // epilogue: p = p0+wm*64+mi*16+l4*4 (+rg contiguous), oc = oc0+wn*64+nj*16+l15
#pragma unroll
  for (int nj = 0; nj < 4; ++nj) {
    int oc = oc0 + wn * 64 + nj * 16 + l15;
    float bias = bproj[oc];
#pragma unroll
    for (int mi = 0; mi < 4; ++mi) {
      int p = p0 + wm * 64 + mi * 16 + l4 * 4;
      size_t idx = ((size_t)(b * C_ + oc)) * HW_ + p;
      float4 xv = *(const float4*)&x[idx];
      float4 ov;
      ov.x = acc[mi][nj][0] + bias + xv.x;
      ov.y = acc[mi][nj][1] + bias + xv.y;
      ov.z = acc[mi][nj][2] + bias + xv.z;
      ov.w = acc[mi][nj][3] + bias + xv.w;
      *(float4*)&out[idx] = ov;
    }
  }
}

extern "C" void kernel_launch(void* const* d_in, const int* in_sizes, int n_in,
                              void* d_out, int out_size, void* d_ws,
                              size_t ws_size, hipStream_t stream) {
  const float* x      = (const float*)d_in[0];
  const float* w_qkv  = (const float*)d_in[1];
  const float* b_qkv  = (const float*)d_in[2];
  const float* w_proj = (const float*)d_in[3];
  const float* b_proj = (const float*)d_in[4];

  char* ws = (char*)d_ws;
  unsigned char*  xp4  = (unsigned char*)(ws + 0);           //  4,734,976
  unsigned char*  w2t4 = (unsigned char*)(ws + 4734976);     //  3,538,944
  unsigned short* wpb  = (unsigned short*)(ws + 8273920);    //    524,288
  unsigned char*  qk8  = (unsigned char*)(ws + 8798208);     // 16,777,216
  unsigned char*  vT8  = (unsigned char*)(ws + 25575424);    //  8,388,608
  unsigned short* hb   = (unsigned short*)(ws + 33964032);   // 16,777,216
  float* out = (float*)d_out;

  zero_border_kernel<<<132, 256, 0, stream>>>(xp4);
  pack_x_kernel<<<dim3(16, 8, 16), 256, 0, stream>>>(x, xp4);
  pack_wqkv_kernel<<<1536, 256, 0, stream>>>(w_qkv, w2t4);
  pack_wproj_kernel<<<1024, 256, 0, stream>>>(w_proj, wpb);
  conv_qkv_kernel<<<dim3(12, 8, 16), 256, 0, stream>>>(xp4, w2t4, b_qkv, qk8, vT8);
  attn_kernel<<<256, 512, 0, stream>>>(qk8, vT8, hb);
  proj_res_kernel<<<dim3(8, 4, 16), 256, 0, stream>>>(hb, wpb, b_proj, x, out);
}